// Round 4
// baseline (671.890 us; speedup 1.0000x reference)
//
#include <hip/hip_runtime.h>

// FFT long conv, register-resident radix-8.
// out[b,d,l] = (1/16384) * linconv(x,f)[l], masked by positions!=-1 (int32 in harness).
// One workgroup (1024 thr) per (b,d) channel; complex FFT 8192 in 64KiB LDS.
// 13 radix-2 DIF stages grouped as 4 register radix-8 passes (strides 1024,128,16,2)
// + final twiddle-free radix-2; inverse mirrors it. Same math/order as the verified
// R2 radix-2 kernel => bit-reversed pointwise logic unchanged.
// XOR swizzle p^((p>>4)&0xE) kills the stride-pattern bank conflicts (bit0 kept so
// (2j,2j+1) pairs stay float4-contiguous).
// R3 bug (fixed): modulation tables held cos/sin(k*pi/16) instead of cos/sin(k*pi/8),
// corrupting the odd-path phase -> absmax 1.8e-2.

#define N_FFT 8192
#define NT    1024
#define PI_F  3.14159265358979323846f
#define RSQ2  0.70710678118654752440f

__device__ __forceinline__ int SW(int p) { return p ^ ((p >> 4) & 0xE); }
__device__ __forceinline__ int rev13(int v) { return (int)(__brev((unsigned)v) >> 19); }

__device__ __forceinline__ float2 cmul(float2 a, float2 b) {
    return make_float2(a.x*b.x - a.y*b.y, a.x*b.y + a.y*b.x);
}
__device__ __forceinline__ float2 cadd(float2 a, float2 b){ return make_float2(a.x+b.x, a.y+b.y); }
__device__ __forceinline__ float2 csub(float2 a, float2 b){ return make_float2(a.x-b.x, a.y-b.y); }

// ---- 3 radix-2 DIF stages (halves 4S,2S,S) on y[k]=a[blk*8S+m+kS]; th=-pi*m/(4S) ----
__device__ __forceinline__ void radix8_fwd(float2 y[8], float th) {
    float sn, cs; __sincosf(th, &sn, &cs);
    float2 c1 = make_float2(cs, sn);
    float2 c2 = cmul(c1, c1);
    float2 c4 = cmul(c2, c2);
    float2 w1 = make_float2(RSQ2*(c1.x + c1.y), RSQ2*(c1.y - c1.x));   // c1*e^{-i pi/4}
    float2 w2 = make_float2(c1.y, -c1.x);                              // c1*(-i)
    float2 w3 = make_float2(RSQ2*(c1.y - c1.x), -RSQ2*(c1.x + c1.y));  // c1*e^{-3i pi/4}
    float2 t0,t1,t2,t3;
    // half = 4S
    t0=csub(y[0],y[4]); y[0]=cadd(y[0],y[4]); y[4]=cmul(t0,c1);
    t1=csub(y[1],y[5]); y[1]=cadd(y[1],y[5]); y[5]=cmul(t1,w1);
    t2=csub(y[2],y[6]); y[2]=cadd(y[2],y[6]); y[6]=cmul(t2,w2);
    t3=csub(y[3],y[7]); y[3]=cadd(y[3],y[7]); y[7]=cmul(t3,w3);
    // half = 2S
    float2 v20 = c2, v21 = make_float2(c2.y, -c2.x);                   // c2, c2*(-i)
    t0=csub(y[0],y[2]); y[0]=cadd(y[0],y[2]); y[2]=cmul(t0,v20);
    t1=csub(y[1],y[3]); y[1]=cadd(y[1],y[3]); y[3]=cmul(t1,v21);
    t2=csub(y[4],y[6]); y[4]=cadd(y[4],y[6]); y[6]=cmul(t2,v20);
    t3=csub(y[5],y[7]); y[5]=cadd(y[5],y[7]); y[7]=cmul(t3,v21);
    // half = S
    t0=csub(y[0],y[1]); y[0]=cadd(y[0],y[1]); y[1]=cmul(t0,c4);
    t1=csub(y[2],y[3]); y[2]=cadd(y[2],y[3]); y[3]=cmul(t1,c4);
    t2=csub(y[4],y[5]); y[4]=cadd(y[4],y[5]); y[5]=cmul(t2,c4);
    t3=csub(y[6],y[7]); y[6]=cadd(y[6],y[7]); y[7]=cmul(t3,c4);
}

// ---- 3 radix-2 DIT stages (halves S,2S,4S); ph=+pi*m/(4S) ----
__device__ __forceinline__ void radix8_inv(float2 y[8], float ph) {
    float sn, cs; __sincosf(ph, &sn, &cs);
    float2 c1 = make_float2(cs, sn);
    float2 c2 = cmul(c1, c1);
    float2 c4 = cmul(c2, c2);
    float2 v;
    // half = S
    v=cmul(y[1],c4); y[1]=csub(y[0],v); y[0]=cadd(y[0],v);
    v=cmul(y[3],c4); y[3]=csub(y[2],v); y[2]=cadd(y[2],v);
    v=cmul(y[5],c4); y[5]=csub(y[4],v); y[4]=cadd(y[4],v);
    v=cmul(y[7],c4); y[7]=csub(y[6],v); y[6]=cadd(y[6],v);
    // half = 2S
    float2 v20 = c2, v21 = make_float2(-c2.y, c2.x);                   // c2, c2*(+i)
    v=cmul(y[2],v20); y[2]=csub(y[0],v); y[0]=cadd(y[0],v);
    v=cmul(y[3],v21); y[3]=csub(y[1],v); y[1]=cadd(y[1],v);
    v=cmul(y[6],v20); y[6]=csub(y[4],v); y[4]=cadd(y[4],v);
    v=cmul(y[7],v21); y[7]=csub(y[5],v); y[5]=cadd(y[5],v);
    // half = 4S
    float2 u1 = make_float2(RSQ2*(c1.x - c1.y), RSQ2*(c1.x + c1.y));   // c1*e^{+i pi/4}
    float2 u2 = make_float2(-c1.y, c1.x);                              // c1*(+i)
    float2 u3 = make_float2(-RSQ2*(c1.x + c1.y), RSQ2*(c1.x - c1.y));  // c1*e^{+3i pi/4}
    v=cmul(y[4],c1); y[4]=csub(y[0],v); y[0]=cadd(y[0],v);
    v=cmul(y[5],u1); y[5]=csub(y[1],v); y[1]=cadd(y[1],v);
    v=cmul(y[6],u2); y[6]=csub(y[2],v); y[2]=cadd(y[2],v);
    v=cmul(y[7],u3); y[7]=csub(y[3],v); y[3]=cadd(y[3],v);
}

template<int LOG2S>
__device__ __forceinline__ void pass_fwd_mid(float2* a, int t) {
    const int S  = 1 << LOG2S;
    const int m  = t & (S - 1);
    const int bs = ((t >> LOG2S) << (LOG2S + 3)) + m;
    float2 y[8];
#pragma unroll
    for (int k = 0; k < 8; ++k) y[k] = a[SW(bs + (k << LOG2S))];
    radix8_fwd(y, -PI_F * (float)m / (float)(4 * S));
#pragma unroll
    for (int k = 0; k < 8; ++k) a[SW(bs + (k << LOG2S))] = y[k];
}

template<int LOG2S>
__device__ __forceinline__ void pass_inv_mid(float2* a, int t) {
    const int S  = 1 << LOG2S;
    const int m  = t & (S - 1);
    const int bs = ((t >> LOG2S) << (LOG2S + 3)) + m;
    float2 y[8];
#pragma unroll
    for (int k = 0; k < 8; ++k) y[k] = a[SW(bs + (k << LOG2S))];
    radix8_inv(y, PI_F * (float)m / (float)(4 * S));
#pragma unroll
    for (int k = 0; k < 8; ++k) a[SW(bs + (k << LOG2S))] = y[k];
}

// Forward FFT: y in pass-A ownership (y[k] = elem t+1024k) -> bit-reversed in LDS.
// Caller must ensure a[] is writable (synced). Ends synced.
__device__ __forceinline__ void fft_fwd8192(float2 y[8], float2* a, int t) {
    radix8_fwd(y, -PI_F * (float)t / 4096.0f);          // S=1024 pass, in regs
#pragma unroll
    for (int k = 0; k < 8; ++k) a[SW(t + (k << 10))] = y[k];
    __syncthreads();
    pass_fwd_mid<7>(a, t); __syncthreads();
    pass_fwd_mid<4>(a, t); __syncthreads();
    pass_fwd_mid<1>(a, t); __syncthreads();
#pragma unroll
    for (int q = 0; q < 4; ++q) {                       // stage 0: twiddle-free radix-2
        const int p = SW(2 * ((q << 10) + t));
        float4 uv = *(const float4*)&a[p];
        *(float4*)&a[p] = make_float4(uv.x + uv.z, uv.y + uv.w, uv.x - uv.z, uv.y - uv.w);
    }
    __syncthreads();
}

// Inverse FFT: bit-reversed in LDS -> natural order in regs (yout[k] = elem t+1024k).
// Caller must be synced on entry. NOT synced on exit (last op is a read).
__device__ __forceinline__ void fft_inv8192(float2 yout[8], float2* a, int t) {
#pragma unroll
    for (int q = 0; q < 4; ++q) {                       // stage 0: twiddle-free radix-2
        const int p = SW(2 * ((q << 10) + t));
        float4 uv = *(const float4*)&a[p];
        *(float4*)&a[p] = make_float4(uv.x + uv.z, uv.y + uv.w, uv.x - uv.z, uv.y - uv.w);
    }
    __syncthreads();
    pass_inv_mid<1>(a, t); __syncthreads();
    pass_inv_mid<4>(a, t); __syncthreads();
    pass_inv_mid<7>(a, t); __syncthreads();
#pragma unroll
    for (int k = 0; k < 8; ++k) yout[k] = a[SW(t + (k << 10))];
    radix8_inv(yout, PI_F * (float)t / 4096.0f);        // S=1024 pass, in regs
}

// Yhat = Xhat*Fhat*scale from combined spectrum values Z1=W_k, Z2=W_{N-k}.
__device__ __forceinline__ float2 pointwise(float2 z1, float2 z2, float scale) {
    float2 X = make_float2(0.5f * (z1.x + z2.x), 0.5f * (z1.y - z2.y));
    float2 D = make_float2(z1.x - z2.x, z1.y + z2.y);
    float2 F = make_float2(0.5f * D.y, -0.5f * D.x);
    float2 Y = cmul(X, F);
    return make_float2(Y.x * scale, Y.y * scale);
}

__global__ void __launch_bounds__(NT)
fftconv_kernel(const float* __restrict__ x, const float* __restrict__ f,
               const int* __restrict__ pos, float* __restrict__ out) {
    __shared__ __align__(16) float2 a[N_FFT];           // 64 KiB
    const int t = threadIdx.x;
    const int c = blockIdx.x;
    const int b = c >> 8;
    const size_t base = (size_t)c * N_FFT;
    const int* pbase = pos + (size_t)b * N_FFT;

    const float scale = 1.0f / (16384.0f * 16384.0f);
    // cos/sin(k*pi/8), k=0..7 (modulation is e^{-i pi (1024k)/8192} = e^{-i pi k/8})
    const float C8[8] = { 1.0f,  0.92387953251128675613f,  0.70710678118654752440f,
                          0.38268343236508977173f,  0.0f, -0.38268343236508977173f,
                         -0.70710678118654752440f, -0.92387953251128675613f};
    const float S8[8] = { 0.0f,  0.38268343236508977173f,  0.70710678118654752440f,
                          0.92387953251128675613f,  1.0f,  0.92387953251128675613f,
                          0.70710678118654752440f,  0.38268343236508977173f};

    float2 w[8], y[8];
    float  yr[8];

    // ---- load: pass-A ownership (elem t + 1024k), coalesced dwords ----
#pragma unroll
    for (int k = 0; k < 8; ++k) {
        const int m = t + (k << 10);
        w[k] = make_float2(x[base + m], f[base + m]);
        y[k] = w[k];
    }

    // ================= even path =================
    fft_fwd8192(y, a, t);

    // pointwise even: global freq 2j; partner handling identical to verified R2
#pragma unroll
    for (int q = 0; q < 4; ++q) {
        const int j = (q << 10) + t;
        if (j == 0) {
            { const int p = SW(0); float2 z = a[p]; a[p] = pointwise(z, z, scale); }
            { const int p = SW(1); float2 z = a[p]; a[p] = pointwise(z, z, scale); }
        } else {
            const int p1 = SW(rev13(j));
            const int p2 = SW(rev13(N_FFT - j));
            float2 z1 = a[p1], z2 = a[p2];
            float2 Y = pointwise(z1, z2, scale);
            a[p1] = Y;
            a[p2] = make_float2(Y.x, -Y.y);
        }
    }
    __syncthreads();

    fft_inv8192(y, a, t);
#pragma unroll
    for (int k = 0; k < 8; ++k) yr[k] = y[k].x;
    __syncthreads();                                    // a[] free for FFT2

    // ================= odd path =================
    // modulate w by e^{-i pi m/8192}, m = t+1024k = (per-thread rot) * (8th-root const)
    float snm, csm; __sincosf(-PI_F * (float)t / 8192.0f, &snm, &csm);
    const float2 rt = make_float2(csm, snm);
#pragma unroll
    for (int k = 0; k < 8; ++k) {
        const float2 rk = cmul(rt, make_float2(C8[k], -S8[k]));
        y[k] = cmul(w[k], rk);
    }
    fft_fwd8192(y, a, t);

    // pointwise odd: global freq 2j+1; all proper pairs
#pragma unroll
    for (int q = 0; q < 4; ++q) {
        const int j = (q << 10) + t;
        const int p1 = SW(rev13(j));
        const int p2 = SW(rev13(N_FFT - 1 - j));
        float2 z1 = a[p1], z2 = a[p2];
        float2 Y = pointwise(z1, z2, scale);
        a[p1] = Y;
        a[p2] = make_float2(Y.x, -Y.y);
    }
    __syncthreads();

    fft_inv8192(y, a, t);                               // y = yo (natural order)

    // ---- combine: out_m = Re(ye_m) + Re(e^{+i pi m/8192} * yo_m), mask, store ----
    const float2 rt2 = make_float2(rt.x, -rt.y);        // conj of modulation rot
#pragma unroll
    for (int k = 0; k < 8; ++k) {
        const int m = t + (k << 10);
        const float2 rk = cmul(rt2, make_float2(C8[k], S8[k]));
        const float val = yr[k] + rk.x * y[k].x - rk.y * y[k].y;
        const float mask = (pbase[m] != -1) ? 1.0f : 0.0f;
        out[base + m] = val * mask;
    }
}

extern "C" void kernel_launch(void* const* d_in, const int* in_sizes, int n_in,
                              void* d_out, int out_size, void* d_ws, size_t ws_size,
                              hipStream_t stream) {
    const float* x   = (const float*)d_in[0];
    const float* f   = (const float*)d_in[1];
    const int*   pos = (const int*)d_in[2];
    float*       out = (float*)d_out;
    (void)in_sizes; (void)n_in; (void)out_size; (void)d_ws; (void)ws_size;

    fftconv_kernel<<<2048, NT, 0, stream>>>(x, f, pos, out);
}

// Round 5
// 665.366 us; speedup vs baseline: 1.0098x; 1.0098x over previous
//
#include <hip/hip_runtime.h>

// FFT long conv, register-resident radix-8.
// out[b,d,l] = (1/16384) * linconv(x,f)[l], masked by positions!=-1 (int32 in harness).
// One workgroup (1024 thr) per (b,d) channel; complex FFT 8192 in 64KiB LDS.
// 13 radix-2 DIF stages grouped as 4 register radix-8 passes (strides 1024,128,16,2)
// + final twiddle-free radix-2; inverse mirrors it.
// XOR swizzle p^((p>>4)&0xE) reduces stride-pattern bank conflicts.
//
// R4 lesson: __launch_bounds__(1024) alone -> compiler caps at 64 VGPR (2 blocks/CU
// target) -> live set ~62 regs spills to scratch -> 2 GB HBM traffic, 576 us.
// Fix: __launch_bounds__(1024, 4) = 4 waves/EU = 1 block/CU -> 128 VGPR budget,
// no spills. LDS (64 KiB) capped us near 1 effective block anyway (Occ 44%).

#define N_FFT 8192
#define NT    1024
#define PI_F  3.14159265358979323846f
#define RSQ2  0.70710678118654752440f

__device__ __forceinline__ int SW(int p) { return p ^ ((p >> 4) & 0xE); }
__device__ __forceinline__ int rev13(int v) { return (int)(__brev((unsigned)v) >> 19); }

__device__ __forceinline__ float2 cmul(float2 a, float2 b) {
    return make_float2(a.x*b.x - a.y*b.y, a.x*b.y + a.y*b.x);
}
__device__ __forceinline__ float2 cadd(float2 a, float2 b){ return make_float2(a.x+b.x, a.y+b.y); }
__device__ __forceinline__ float2 csub(float2 a, float2 b){ return make_float2(a.x-b.x, a.y-b.y); }

// ---- 3 radix-2 DIF stages (halves 4S,2S,S) on y[k]=a[blk*8S+m+kS]; th=-pi*m/(4S) ----
__device__ __forceinline__ void radix8_fwd(float2 y[8], float th) {
    float sn, cs; __sincosf(th, &sn, &cs);
    float2 c1 = make_float2(cs, sn);
    float2 c2 = cmul(c1, c1);
    float2 c4 = cmul(c2, c2);
    float2 w1 = make_float2(RSQ2*(c1.x + c1.y), RSQ2*(c1.y - c1.x));   // c1*e^{-i pi/4}
    float2 w2 = make_float2(c1.y, -c1.x);                              // c1*(-i)
    float2 w3 = make_float2(RSQ2*(c1.y - c1.x), -RSQ2*(c1.x + c1.y));  // c1*e^{-3i pi/4}
    float2 t0,t1,t2,t3;
    // half = 4S
    t0=csub(y[0],y[4]); y[0]=cadd(y[0],y[4]); y[4]=cmul(t0,c1);
    t1=csub(y[1],y[5]); y[1]=cadd(y[1],y[5]); y[5]=cmul(t1,w1);
    t2=csub(y[2],y[6]); y[2]=cadd(y[2],y[6]); y[6]=cmul(t2,w2);
    t3=csub(y[3],y[7]); y[3]=cadd(y[3],y[7]); y[7]=cmul(t3,w3);
    // half = 2S
    float2 v20 = c2, v21 = make_float2(c2.y, -c2.x);                   // c2, c2*(-i)
    t0=csub(y[0],y[2]); y[0]=cadd(y[0],y[2]); y[2]=cmul(t0,v20);
    t1=csub(y[1],y[3]); y[1]=cadd(y[1],y[3]); y[3]=cmul(t1,v21);
    t2=csub(y[4],y[6]); y[4]=cadd(y[4],y[6]); y[6]=cmul(t2,v20);
    t3=csub(y[5],y[7]); y[5]=cadd(y[5],y[7]); y[7]=cmul(t3,v21);
    // half = S
    t0=csub(y[0],y[1]); y[0]=cadd(y[0],y[1]); y[1]=cmul(t0,c4);
    t1=csub(y[2],y[3]); y[2]=cadd(y[2],y[3]); y[3]=cmul(t1,c4);
    t2=csub(y[4],y[5]); y[4]=cadd(y[4],y[5]); y[5]=cmul(t2,c4);
    t3=csub(y[6],y[7]); y[6]=cadd(y[6],y[7]); y[7]=cmul(t3,c4);
}

// ---- 3 radix-2 DIT stages (halves S,2S,4S); ph=+pi*m/(4S) ----
__device__ __forceinline__ void radix8_inv(float2 y[8], float ph) {
    float sn, cs; __sincosf(ph, &sn, &cs);
    float2 c1 = make_float2(cs, sn);
    float2 c2 = cmul(c1, c1);
    float2 c4 = cmul(c2, c2);
    float2 v;
    // half = S
    v=cmul(y[1],c4); y[1]=csub(y[0],v); y[0]=cadd(y[0],v);
    v=cmul(y[3],c4); y[3]=csub(y[2],v); y[2]=cadd(y[2],v);
    v=cmul(y[5],c4); y[5]=csub(y[4],v); y[4]=cadd(y[4],v);
    v=cmul(y[7],c4); y[7]=csub(y[6],v); y[6]=cadd(y[6],v);
    // half = 2S
    float2 v20 = c2, v21 = make_float2(-c2.y, c2.x);                   // c2, c2*(+i)
    v=cmul(y[2],v20); y[2]=csub(y[0],v); y[0]=cadd(y[0],v);
    v=cmul(y[3],v21); y[3]=csub(y[1],v); y[1]=cadd(y[1],v);
    v=cmul(y[6],v20); y[6]=csub(y[4],v); y[4]=cadd(y[4],v);
    v=cmul(y[7],v21); y[7]=csub(y[5],v); y[5]=cadd(y[5],v);
    // half = 4S
    float2 u1 = make_float2(RSQ2*(c1.x - c1.y), RSQ2*(c1.x + c1.y));   // c1*e^{+i pi/4}
    float2 u2 = make_float2(-c1.y, c1.x);                              // c1*(+i)
    float2 u3 = make_float2(-RSQ2*(c1.x + c1.y), RSQ2*(c1.x - c1.y));  // c1*e^{+3i pi/4}
    v=cmul(y[4],c1); y[4]=csub(y[0],v); y[0]=cadd(y[0],v);
    v=cmul(y[5],u1); y[5]=csub(y[1],v); y[1]=cadd(y[1],v);
    v=cmul(y[6],u2); y[6]=csub(y[2],v); y[2]=cadd(y[2],v);
    v=cmul(y[7],u3); y[7]=csub(y[3],v); y[3]=cadd(y[3],v);
}

template<int LOG2S>
__device__ __forceinline__ void pass_fwd_mid(float2* a, int t) {
    const int S  = 1 << LOG2S;
    const int m  = t & (S - 1);
    const int bs = ((t >> LOG2S) << (LOG2S + 3)) + m;
    float2 y[8];
#pragma unroll
    for (int k = 0; k < 8; ++k) y[k] = a[SW(bs + (k << LOG2S))];
    radix8_fwd(y, -PI_F * (float)m / (float)(4 * S));
#pragma unroll
    for (int k = 0; k < 8; ++k) a[SW(bs + (k << LOG2S))] = y[k];
}

template<int LOG2S>
__device__ __forceinline__ void pass_inv_mid(float2* a, int t) {
    const int S  = 1 << LOG2S;
    const int m  = t & (S - 1);
    const int bs = ((t >> LOG2S) << (LOG2S + 3)) + m;
    float2 y[8];
#pragma unroll
    for (int k = 0; k < 8; ++k) y[k] = a[SW(bs + (k << LOG2S))];
    radix8_inv(y, PI_F * (float)m / (float)(4 * S));
#pragma unroll
    for (int k = 0; k < 8; ++k) a[SW(bs + (k << LOG2S))] = y[k];
}

// Forward FFT: y in pass-A ownership (y[k] = elem t+1024k) -> bit-reversed in LDS.
// Caller must ensure a[] is writable (synced). Ends synced.
__device__ __forceinline__ void fft_fwd8192(float2 y[8], float2* a, int t) {
    radix8_fwd(y, -PI_F * (float)t / 4096.0f);          // S=1024 pass, in regs
#pragma unroll
    for (int k = 0; k < 8; ++k) a[SW(t + (k << 10))] = y[k];
    __syncthreads();
    pass_fwd_mid<7>(a, t); __syncthreads();
    pass_fwd_mid<4>(a, t); __syncthreads();
    pass_fwd_mid<1>(a, t); __syncthreads();
#pragma unroll
    for (int q = 0; q < 4; ++q) {                       // stage 0: twiddle-free radix-2
        const int p = SW(2 * ((q << 10) + t));
        float4 uv = *(const float4*)&a[p];
        *(float4*)&a[p] = make_float4(uv.x + uv.z, uv.y + uv.w, uv.x - uv.z, uv.y - uv.w);
    }
    __syncthreads();
}

// Inverse FFT: bit-reversed in LDS -> natural order in regs (yout[k] = elem t+1024k).
// Caller must be synced on entry. NOT synced on exit (last op is a read).
__device__ __forceinline__ void fft_inv8192(float2 yout[8], float2* a, int t) {
#pragma unroll
    for (int q = 0; q < 4; ++q) {                       // stage 0: twiddle-free radix-2
        const int p = SW(2 * ((q << 10) + t));
        float4 uv = *(const float4*)&a[p];
        *(float4*)&a[p] = make_float4(uv.x + uv.z, uv.y + uv.w, uv.x - uv.z, uv.y - uv.w);
    }
    __syncthreads();
    pass_inv_mid<1>(a, t); __syncthreads();
    pass_inv_mid<4>(a, t); __syncthreads();
    pass_inv_mid<7>(a, t); __syncthreads();
#pragma unroll
    for (int k = 0; k < 8; ++k) yout[k] = a[SW(t + (k << 10))];
    radix8_inv(yout, PI_F * (float)t / 4096.0f);        // S=1024 pass, in regs
}

// Yhat = Xhat*Fhat*scale from combined spectrum values Z1=W_k, Z2=W_{N-k}.
__device__ __forceinline__ float2 pointwise(float2 z1, float2 z2, float scale) {
    float2 X = make_float2(0.5f * (z1.x + z2.x), 0.5f * (z1.y - z2.y));
    float2 D = make_float2(z1.x - z2.x, z1.y + z2.y);
    float2 F = make_float2(0.5f * D.y, -0.5f * D.x);
    float2 Y = cmul(X, F);
    return make_float2(Y.x * scale, Y.y * scale);
}

__global__ void __launch_bounds__(NT, 4)   // 4 waves/EU = 1 block/CU -> 128 VGPR cap, no spills
fftconv_kernel(const float* __restrict__ x, const float* __restrict__ f,
               const int* __restrict__ pos, float* __restrict__ out) {
    __shared__ __align__(16) float2 a[N_FFT];           // 64 KiB
    const int t = threadIdx.x;
    const int c = blockIdx.x;
    const int b = c >> 8;
    const size_t base = (size_t)c * N_FFT;
    const int* pbase = pos + (size_t)b * N_FFT;

    const float scale = 1.0f / (16384.0f * 16384.0f);
    // cos/sin(k*pi/8), k=0..7 (modulation is e^{-i pi (1024k)/8192} = e^{-i pi k/8})
    const float C8[8] = { 1.0f,  0.92387953251128675613f,  0.70710678118654752440f,
                          0.38268343236508977173f,  0.0f, -0.38268343236508977173f,
                         -0.70710678118654752440f, -0.92387953251128675613f};
    const float S8[8] = { 0.0f,  0.38268343236508977173f,  0.70710678118654752440f,
                          0.92387953251128675613f,  1.0f,  0.92387953251128675613f,
                          0.70710678118654752440f,  0.38268343236508977173f};

    float2 w[8], y[8];
    float  yr[8];

    // ---- load: pass-A ownership (elem t + 1024k), coalesced dwords ----
#pragma unroll
    for (int k = 0; k < 8; ++k) {
        const int m = t + (k << 10);
        w[k] = make_float2(x[base + m], f[base + m]);
        y[k] = w[k];
    }

    // ================= even path =================
    fft_fwd8192(y, a, t);

    // pointwise even: global freq 2j; partner handling identical to verified R2
#pragma unroll
    for (int q = 0; q < 4; ++q) {
        const int j = (q << 10) + t;
        if (j == 0) {
            { const int p = SW(0); float2 z = a[p]; a[p] = pointwise(z, z, scale); }
            { const int p = SW(1); float2 z = a[p]; a[p] = pointwise(z, z, scale); }
        } else {
            const int p1 = SW(rev13(j));
            const int p2 = SW(rev13(N_FFT - j));
            float2 z1 = a[p1], z2 = a[p2];
            float2 Y = pointwise(z1, z2, scale);
            a[p1] = Y;
            a[p2] = make_float2(Y.x, -Y.y);
        }
    }
    __syncthreads();

    fft_inv8192(y, a, t);
#pragma unroll
    for (int k = 0; k < 8; ++k) yr[k] = y[k].x;
    __syncthreads();                                    // a[] free for FFT2

    // ================= odd path =================
    // modulate w by e^{-i pi m/8192}, m = t+1024k = (per-thread rot) * (8th-root const)
    float snm, csm; __sincosf(-PI_F * (float)t / 8192.0f, &snm, &csm);
    const float2 rt = make_float2(csm, snm);
#pragma unroll
    for (int k = 0; k < 8; ++k) {
        const float2 rk = cmul(rt, make_float2(C8[k], -S8[k]));
        y[k] = cmul(w[k], rk);
    }
    fft_fwd8192(y, a, t);

    // pointwise odd: global freq 2j+1; all proper pairs
#pragma unroll
    for (int q = 0; q < 4; ++q) {
        const int j = (q << 10) + t;
        const int p1 = SW(rev13(j));
        const int p2 = SW(rev13(N_FFT - 1 - j));
        float2 z1 = a[p1], z2 = a[p2];
        float2 Y = pointwise(z1, z2, scale);
        a[p1] = Y;
        a[p2] = make_float2(Y.x, -Y.y);
    }
    __syncthreads();

    fft_inv8192(y, a, t);                               // y = yo (natural order)

    // ---- combine: out_m = Re(ye_m) + Re(e^{+i pi m/8192} * yo_m), mask, store ----
    const float2 rt2 = make_float2(rt.x, -rt.y);        // conj of modulation rot
#pragma unroll
    for (int k = 0; k < 8; ++k) {
        const int m = t + (k << 10);
        const float2 rk = cmul(rt2, make_float2(C8[k], S8[k]));
        const float val = yr[k] + rk.x * y[k].x - rk.y * y[k].y;
        const float mask = (pbase[m] != -1) ? 1.0f : 0.0f;
        out[base + m] = val * mask;
    }
}

extern "C" void kernel_launch(void* const* d_in, const int* in_sizes, int n_in,
                              void* d_out, int out_size, void* d_ws, size_t ws_size,
                              hipStream_t stream) {
    const float* x   = (const float*)d_in[0];
    const float* f   = (const float*)d_in[1];
    const int*   pos = (const int*)d_in[2];
    float*       out = (float*)d_out;
    (void)in_sizes; (void)n_in; (void)out_size; (void)d_ws; (void)ws_size;

    fftconv_kernel<<<2048, NT, 0, stream>>>(x, f, pos, out);
}